// Round 2
// baseline (2878.894 us; speedup 1.0000x reference)
//
#include <hip/hip_runtime.h>
#include <hip/hip_bf16.h>

typedef __hip_bfloat16 bf16;

#define BDIM 8
#define CDIM 128
#define TDIM 32768
#define LDIM 256
#define HOP 128
#define SLOPE 0.2f

__device__ __forceinline__ float b2f(bf16 v) { return __bfloat162float(v); }
__device__ __forceinline__ bf16 f2b(float v) { return __float2bfloat16(v); }
__device__ __forceinline__ float lrelu(float v) { return v > 0.f ? v : SLOPE * v; }

// ---------------------------------------------------------------------------
// Kernel 0: weight-norm for the dilated conv.  wn[c][i][k] = g[c]*v[c][i][k]/||v[c]||_F
// ---------------------------------------------------------------------------
__global__ void wnorm_kernel(const float* __restrict__ v, const float* __restrict__ g,
                             float* __restrict__ wn) {
    int c = blockIdx.x;      // 128 blocks
    int t = threadIdx.x;     // 128 threads
    __shared__ float red[128];
    float s = 0.f;
    for (int e = t; e < 384; e += 128) {
        float x = v[c * 384 + e];
        s += x * x;
    }
    red[t] = s;
    __syncthreads();
    for (int off = 64; off > 0; off >>= 1) {
        if (t < off) red[t] += red[t + off];
        __syncthreads();
    }
    float scale = g[c] / sqrtf(red[0]);
    for (int e = t; e < 384; e += 128) {
        wn[c * 384 + e] = scale * v[c * 384 + e];
    }
}

// ---------------------------------------------------------------------------
// Kernel 1: location-variable conv + bias + leaky-relu -> h (bf16, workspace)
// One block per (b, l): GEMM  O[o][s] = sum_{i,k} W[b,i,o,k,l] * xseg[i][s+k]
// Thread: 4 consecutive s (sg*4) x 16 o (og*16); fp32 accumulate.
// ---------------------------------------------------------------------------
__global__ void __launch_bounds__(256, 2)
lvc_kernel(const float* __restrict__ x, const float* __restrict__ w,
           const float* __restrict__ bias, bf16* __restrict__ h) {
    __shared__ float xseg[CDIM * 130];     // 66.56 KB
    __shared__ float wlds[8 * 3 * CDIM];   // 12 KB   [ii][kk][o]

    // XCD-swizzle: blocks sharing weight cache lines (same b, consecutive l)
    // get identical p%8 so (round-robin dispatch) they share one XCD's L2.
    int p = blockIdx.x;
    int b = p >> 8;
    int l = (p & 7) * 32 + ((p >> 3) & 31);
    int t = threadIdx.x;

    // ---- stage x segment: xseg[i][pp] = x[b,i, l*128 + pp - 1], zero-padded
    int xbase = l * HOP - 1;
    for (int e = t; e < CDIM * 130; e += 256) {
        int i = e / 130;
        int pp = e - i * 130;
        int gpos = xbase + pp;
        float val = 0.f;
        if ((unsigned)gpos < (unsigned)TDIM)
            val = x[(size_t)(b * CDIM + i) * TDIM + gpos];
        xseg[e] = val;
    }

    int sg = t & 31, og = t >> 5;
    int s0 = sg * 4;
    int ob = og * 16;

    float acc[4][16];
#pragma unroll
    for (int u = 0; u < 4; u++)
#pragma unroll
        for (int j = 0; j < 16; j++) acc[u][j] = 0.f;

    for (int ic = 0; ic < 16; ic++) {
        __syncthreads();   // staging done / previous chunk consumed
        int i0 = ic * 8;
        // ---- stage weight chunk: wlds[ii][kk][o] = W[b, i0+ii, o, kk, l]
        for (int e = t; e < 3072; e += 256) {
            int ii = e / 384;
            int r = e - ii * 384;
            int o = r / 3;
            int kk = r - o * 3;
            size_t widx = ((((size_t)(b * CDIM + i0 + ii)) * CDIM + o) * 3 + kk) * LDIM + l;
            wlds[(ii * 3 + kk) * CDIM + o] = w[widx];
        }
        __syncthreads();
        // ---- compute
#pragma unroll
        for (int ii = 0; ii < 8; ii++) {
            int i = i0 + ii;
            const float* xp = &xseg[i * 130 + s0];
            float2 xv01 = *(const float2*)&xp[0];
            float2 xv23 = *(const float2*)&xp[2];
            float2 xv45 = *(const float2*)&xp[4];
            float xv[6] = {xv01.x, xv01.y, xv23.x, xv23.y, xv45.x, xv45.y};
            const float* wp = &wlds[ii * 3 * CDIM + ob];
#pragma unroll
            for (int o4 = 0; o4 < 4; o4++) {
                float4 w0 = *(const float4*)&wp[0 * CDIM + o4 * 4];
                float4 w1 = *(const float4*)&wp[1 * CDIM + o4 * 4];
                float4 w2 = *(const float4*)&wp[2 * CDIM + o4 * 4];
#pragma unroll
                for (int u = 0; u < 4; u++) {
                    float xa = xv[u], xb = xv[u + 1], xc = xv[u + 2];
                    acc[u][o4 * 4 + 0] += w0.x * xa + w1.x * xb + w2.x * xc;
                    acc[u][o4 * 4 + 1] += w0.y * xa + w1.y * xb + w2.y * xc;
                    acc[u][o4 * 4 + 2] += w0.z * xa + w1.z * xb + w2.z * xc;
                    acc[u][o4 * 4 + 3] += w0.w * xa + w1.w * xb + w2.w * xc;
                }
            }
        }
    }

    // ---- epilogue: + bias[b,o,l], leaky-relu, store bf16 h[b,o,l*128+s]
#pragma unroll
    for (int j = 0; j < 16; j++) {
        int o = ob + j;
        float bs = bias[((size_t)b * CDIM + o) * LDIM + l];
        union { ushort4 u4; bf16 v[4]; } pk;
#pragma unroll
        for (int u = 0; u < 4; u++) pk.v[u] = f2b(lrelu(acc[u][j] + bs));
        *(ushort4*)&h[((size_t)(b * CDIM + o)) * TDIM + l * HOP + s0] = pk.u4;
    }
}

// ---------------------------------------------------------------------------
// Kernel 2: dilated (3, dilation 3) conv + conv_b + leaky-relu -> out (fp32)
// out[b,c,t] = lrelu( cb[c] + sum_{i,kk} wn[c,i,kk] * h[b,i,t+3*kk-3] )
// One block per (b, 128-wide t tile).
// ---------------------------------------------------------------------------
__global__ void __launch_bounds__(256, 2)
dconv_kernel(const bf16* __restrict__ hws, const float* __restrict__ wn,
             const float* __restrict__ cb, float* __restrict__ out) {
    __shared__ float ht[CDIM * 134];       // 68.6 KB
    __shared__ float wlds[4 * 3 * CDIM];   // 6 KB   [ii][kk][c]

    int bid = blockIdx.x;
    int b = bid >> 8;
    int t0 = (bid & 255) * 128;
    int t = threadIdx.x;

    // ---- stage h tile: ht[i][pp] = h[b,i, t0 + pp - 3], zero-padded
    for (int e = t; e < CDIM * 134; e += 256) {
        int i = e / 134;
        int pp = e - i * 134;
        int gpos = t0 + pp - 3;
        float val = 0.f;
        if ((unsigned)gpos < (unsigned)TDIM)
            val = b2f(hws[(size_t)(b * CDIM + i) * TDIM + gpos]);
        ht[e] = val;
    }

    int sg = t & 31, cg = t >> 5;
    int s0 = sg * 4;
    int c0 = cg * 16;

    float acc[4][16];
#pragma unroll
    for (int u = 0; u < 4; u++)
#pragma unroll
        for (int j = 0; j < 16; j++) acc[u][j] = 0.f;

    for (int ic = 0; ic < 32; ic++) {
        __syncthreads();
        int i0 = ic * 4;
        // ---- stage wn chunk: wlds[ii][kk][c] = wn[c, i0+ii, kk]
        for (int e = t; e < 4 * 3 * CDIM; e += 256) {
            int c = e / 12;
            int r = e - c * 12;
            int ii = r / 3;
            int kk = r - ii * 3;
            wlds[(ii * 3 + kk) * CDIM + c] = wn[c * 384 + (i0 + ii) * 3 + kk];
        }
        __syncthreads();
#pragma unroll
        for (int ii = 0; ii < 4; ii++) {
            int i = i0 + ii;
            const float* hp = &ht[i * 134 + s0];
            float xv[10];
#pragma unroll
            for (int q = 0; q < 5; q++) {
                float2 v2 = *(const float2*)&hp[q * 2];
                xv[q * 2] = v2.x;
                xv[q * 2 + 1] = v2.y;
            }
            const float* wp = &wlds[ii * 3 * CDIM + c0];
#pragma unroll
            for (int o4 = 0; o4 < 4; o4++) {
                float4 w0 = *(const float4*)&wp[0 * CDIM + o4 * 4];
                float4 w1 = *(const float4*)&wp[1 * CDIM + o4 * 4];
                float4 w2 = *(const float4*)&wp[2 * CDIM + o4 * 4];
#pragma unroll
                for (int u = 0; u < 4; u++) {
                    float xa = xv[u], xb = xv[u + 3], xc = xv[u + 6];
                    acc[u][o4 * 4 + 0] += w0.x * xa + w1.x * xb + w2.x * xc;
                    acc[u][o4 * 4 + 1] += w0.y * xa + w1.y * xb + w2.y * xc;
                    acc[u][o4 * 4 + 2] += w0.z * xa + w1.z * xb + w2.z * xc;
                    acc[u][o4 * 4 + 3] += w0.w * xa + w1.w * xb + w2.w * xc;
                }
            }
        }
    }

    // ---- epilogue: + conv_b[c], leaky-relu, store fp32 out[b,c,t0+s]
#pragma unroll
    for (int j = 0; j < 16; j++) {
        int c = c0 + j;
        float bc = cb[c];
        float4 pk;
        pk.x = lrelu(acc[0][j] + bc);
        pk.y = lrelu(acc[1][j] + bc);
        pk.z = lrelu(acc[2][j] + bc);
        pk.w = lrelu(acc[3][j] + bc);
        *(float4*)&out[((size_t)(b * CDIM + c)) * TDIM + t0 + s0] = pk;
    }
}

// ---------------------------------------------------------------------------
extern "C" void kernel_launch(void* const* d_in, const int* in_sizes, int n_in,
                              void* d_out, int out_size, void* d_ws, size_t ws_size,
                              hipStream_t stream) {
    const float* x      = (const float*)d_in[0];
    const float* weight = (const float*)d_in[1];
    const float* bias   = (const float*)d_in[2];
    const float* conv_v = (const float*)d_in[3];
    const float* conv_g = (const float*)d_in[4];
    const float* conv_b = (const float*)d_in[5];
    float* out = (float*)d_out;

    // workspace layout: [0, 192KiB) wn (fp32) ; [256KiB, 256KiB+64MiB) h (bf16)
    float* wn = (float*)d_ws;
    bf16* h = (bf16*)((char*)d_ws + (size_t)262144);

    wnorm_kernel<<<dim3(128), dim3(128), 0, stream>>>(conv_v, conv_g, wn);
    lvc_kernel<<<dim3(2048), dim3(256), 0, stream>>>(x, weight, bias, h);
    dconv_kernel<<<dim3(2048), dim3(256), 0, stream>>>(h, wn, conv_b, out);
}